// Round 16
// baseline (89.187 us; speedup 1.0000x reference)
//
#include <hip/hip_runtime.h>
#include <hip/hip_bf16.h>

#define D_MODEL 512
#define D_STATE 32
#define BATCH 8
#define SEQ 4096
#define MROWS (BATCH * SEQ)

typedef __bf16 bf16;
typedef __bf16 bf16x4 __attribute__((ext_vector_type(4)));
typedef __bf16 bf16x8 __attribute__((ext_vector_type(8)));
typedef float f32x4 __attribute__((ext_vector_type(4)));
typedef _Float16 half_t;
typedef _Float16 half2_t __attribute__((ext_vector_type(2)));
typedef _Float16 half8 __attribute__((ext_vector_type(8)));

#define CHUNK 16
#define BURN 64
#define NCHUNK (SEQ / CHUNK)   // 256 chunks per batch, 2048 chains

__device__ __forceinline__ bf16x8 cvt8(const f32x4 a, const f32x4 b) {
  bf16x8 h;
  h[0] = (bf16)a[0]; h[1] = (bf16)a[1]; h[2] = (bf16)a[2]; h[3] = (bf16)a[3];
  h[4] = (bf16)b[0]; h[5] = (bf16)b[1]; h[6] = (bf16)b[2]; h[7] = (bf16)b[3];
  return h;
}

// ================= k_pre: block 0 = dt/X/A_bar/XTs; blocks 1..16 CW; 17..32 WD ============
__global__ __launch_bounds__(256) void k_pre(
    const float* __restrict__ A, const float* __restrict__ C, const float* __restrict__ Dv,
    const float* __restrict__ log_dt, const float* __restrict__ W,
    float* __restrict__ A_bar, float* __restrict__ XTs,
    bf16* __restrict__ CW, bf16* __restrict__ WD) {
  __shared__ float Xs[32][32];
  const int bid = blockIdx.x, t = threadIdx.x;
  float* Xf = &Xs[0][0];

  if (bid == 0) {
    {
      float v0 = __expf(log_dt[t]);
      float v1 = __expf(log_dt[t + 256]);
      v0 = fminf(fmaxf(v0, 1e-4f), 1.0f);
      v1 = fminf(fmaxf(v1, 1e-4f), 1.0f);
      Xf[t] = v0 + v1;
    }
    __syncthreads();
    for (int s2 = 128; s2 > 0; s2 >>= 1) {
      if (t < s2) Xf[t] += Xf[t + s2];
      __syncthreads();
    }
    const float dtv = Xf[0] * (1.0f / 512.0f);
    __syncthreads();
    {
      const int i0 = 4 * t;
      const f32x4 av = *(const f32x4*)(A + i0);
      f32x4 mv;
#pragma unroll
      for (int q = 0; q < 4; q++) {
        const int r = (i0 + q) >> 5, c = (i0 + q) & 31;
        mv[q] = (r == c ? 1.0f : 0.0f) - 0.5f * dtv * av[q];
      }
      *(f32x4*)(Xf + i0) = mv;
    }
    __syncthreads();
    if (t < 32) {
      const int j = t;
      float xcol[32];
#pragma unroll
      for (int i = 0; i < 32; i++) {
        float s0 = 0.f, s1 = 0.f, s2 = 0.f, s3 = 0.f;
#pragma unroll
        for (int k = 0; k < 32; k += 4) {
          if (k < i)     s0 -= Xf[i * 32 + k]     * xcol[k];
          if (k + 1 < i) s1 -= Xf[i * 32 + k + 1] * xcol[k + 1];
          if (k + 2 < i) s2 -= Xf[i * 32 + k + 2] * xcol[k + 2];
          if (k + 3 < i) s3 -= Xf[i * 32 + k + 3] * xcol[k + 3];
        }
        const float num = (i == j ? 1.0f : 0.0f) + ((s0 + s1) + (s2 + s3));
        xcol[i] = (i >= j) ? num / Xf[i * 32 + i] : 0.0f;
      }
#pragma unroll
      for (int i = 0; i < 32; i++) Xs[i][j] = xcol[i];
    }
    __syncthreads();
    {
      const int i0 = 4 * t;
      const int r = t >> 3;
      f32x4 ov;
#pragma unroll
      for (int q = 0; q < 4; q++) {
        const int c = (i0 + q) & 31;
        float s = 0.f;
#pragma unroll
        for (int k = 0; k < 32; k++) {
          const float p2 = (r == k ? 1.0f : 0.0f) + 0.5f * dtv * A[r * 32 + k];
          s = fmaf(p2, Xf[k * 32 + c], s);
        }
        ov[q] = s;
      }
      *(f32x4*)(A_bar + i0) = ov;
    }
#pragma unroll
    for (int i = 0; i < 4; i++) {
      const int idx = t + i * 256;
      const int k = idx >> 5, n = idx & 31;
      XTs[idx] = dtv * Xf[n * 32 + k];
    }
  } else if (bid <= 16) {
    const int w = t >> 6, lane = t & 63;
    const int l15 = lane & 15, kg = lane >> 4;
    const int m = w & 1, nf = w >> 1;
    const int eb = (bid - 1) * 32;
    const float* wp = W + (long)(eb + m * 16 + l15) * D_MODEL + kg * 8;
    const int ncol = nf * 16 + l15;
    f32x4 acc = (f32x4)(0.0f);
#pragma unroll 1
    for (int kt = 0; kt < 16; kt++) {
      const f32x4 w0 = *(const f32x4*)(wp + kt * 32);
      const f32x4 w1 = *(const f32x4*)(wp + kt * 32 + 4);
      const bf16x8 af = cvt8(w0, w1);
      bf16x8 bf;
#pragma unroll
      for (int j = 0; j < 8; j++)
        bf[j] = (bf16)C[(kt * 32 + kg * 8 + j) * D_STATE + ncol];
      acc = __builtin_amdgcn_mfma_f32_16x16x32_bf16(af, bf, acc, 0, 0, 0);
    }
#pragma unroll
    for (int jj = 0; jj < 4; jj++)
      CW[(eb + m * 16 + kg * 4 + jj) * D_STATE + ncol] = (bf16)acc[jj];
  } else {
#pragma unroll
    for (int jj = 0; jj < 16; jj++) {
      const int i = (bid - 17) * 16384 + jj * 1024 + t * 4;
      const f32x4 wv = *(const f32x4*)(W + i);
      const f32x4 dv = *(const f32x4*)(Dv + (i & 511));
      bf16x4 h;
#pragma unroll
      for (int q = 0; q < 4; q++) h[q] = (bf16)(wv[q] * dv[q]);
      *(bf16x4*)(WD + i) = h;
    }
  }
}

// ========= k_uB: BK=64 phases (8 barriers), 3 blocks/CU, global_load_lds staging =========
// Stage x[64 rows][64 cols] f32 (16 KB) per phase, XOR slot-swizzle (slot^row&15) via
// pre-swizzled source; read with same XOR -> 2-way bank alias (free). 2 kt per phase.
__device__ __forceinline__ void stage_x2(const float* __restrict__ x, long rowbase,
                                         int ph, void* lds, int t) {
#pragma unroll
  for (int j = 0; j < 4; j++) {
    const int boff = j * 4096 + t * 16;        // physical LDS byte this lane fills
    const int r = boff >> 8;                   // tile row (256 B per row: 64 f32)
    const int s = (boff >> 4) & 15;            // physical 16B slot within row
    const int cb = (s ^ (r & 15)) << 4;        // swizzled source slot
    const char* src = (const char*)(x + (rowbase + r) * D_MODEL) + ph * 256 + cb;
    const int udst = j * 4096 + ((t >> 6) << 10);  // wave-uniform dest (+lane*16 by HW)
    __builtin_amdgcn_global_load_lds(
        (const __attribute__((address_space(1))) void*)src,
        (__attribute__((address_space(3))) void*)((char*)lds + udst), 16, 0, 0);
  }
}

__global__ __launch_bounds__(256, 3) void k_uB(
    const float* __restrict__ x, const float* __restrict__ B,
    const float* __restrict__ XTs,
    float* __restrict__ uB, bf16* __restrict__ xb) {
  __shared__ float xs[2][64 * 64];   // 2 x 16 KB staged x tiles
  __shared__ float sXT[1024];        // dt*X^T, 4 KB
  __shared__ float srw[64 * 33];     // s_raw transpose, 8.25 KB
  const int t = threadIdx.x, w = t >> 6, lane = t & 63;
  const int l15 = lane & 15, kg = lane >> 4;
  const long rowbase = (long)blockIdx.x * 64;

#pragma unroll
  for (int i = 0; i < 4; i++) sXT[t + i * 256] = XTs[t + i * 256];

  const int arow = w * 16 + l15;     // wave w owns rows [w*16, w*16+16)
  bf16* xo = xb + (rowbase + arow) * D_MODEL + kg * 8;
  const float* bp0 = B + l15 * D_MODEL + kg * 8;
  const float* bp1 = B + (16 + l15) * D_MODEL + kg * 8;
  const int rkey = arow & 15;

  f32x4 acc0 = (f32x4)(0.0f), acc1 = (f32x4)(0.0f);
  f32x4 cb0, cb1, cb2, cb3, nb0, nb1, nb2, nb3;

  stage_x2(x, rowbase, 0, &xs[0][0], t);
  cb0 = *(const f32x4*)(bp0); cb1 = *(const f32x4*)(bp0 + 4);
  cb2 = *(const f32x4*)(bp1); cb3 = *(const f32x4*)(bp1 + 4);

#pragma unroll 1
  for (int ph = 0; ph < 8; ph++) {
    __syncthreads();   // drains stage of buf[ph&1]
    if (ph < 7) stage_x2(x, rowbase, ph + 1, &xs[(ph + 1) & 1][0], t);
    const float* xbuf = &xs[ph & 1][arow * 64];
#pragma unroll
    for (int h = 0; h < 2; h++) {
      const int kt = ph * 2 + h;
      if (kt < 15) {
        const int o = (kt + 1) * 32;
        nb0 = *(const f32x4*)(bp0 + o); nb1 = *(const f32x4*)(bp0 + o + 4);
        nb2 = *(const f32x4*)(bp1 + o); nb3 = *(const f32x4*)(bp1 + o + 4);
      }
      const int sl0 = ((h * 8 + kg * 2) ^ rkey) << 2;
      const int sl1 = ((h * 8 + kg * 2 + 1) ^ rkey) << 2;
      const f32x4 a0 = *(const f32x4*)(xbuf + sl0);
      const f32x4 a1 = *(const f32x4*)(xbuf + sl1);
      const bf16x8 af = cvt8(a0, a1);
      *(bf16x8*)(xo + kt * 32) = af;
      const bf16x8 bh0 = cvt8(cb0, cb1);
      const bf16x8 bh1 = cvt8(cb2, cb3);
      bf16x8 bl0, bl1;
#pragma unroll
      for (int q = 0; q < 4; q++) {
        bl0[q]     = (bf16)(cb0[q] - (float)bh0[q]);
        bl0[q + 4] = (bf16)(cb1[q] - (float)bh0[q + 4]);
        bl1[q]     = (bf16)(cb2[q] - (float)bh1[q]);
        bl1[q + 4] = (bf16)(cb3[q] - (float)bh1[q + 4]);
      }
      acc0 = __builtin_amdgcn_mfma_f32_16x16x32_bf16(af, bh0, acc0, 0, 0, 0);
      acc0 = __builtin_amdgcn_mfma_f32_16x16x32_bf16(af, bl0, acc0, 0, 0, 0);
      acc1 = __builtin_amdgcn_mfma_f32_16x16x32_bf16(af, bh1, acc1, 0, 0, 0);
      acc1 = __builtin_amdgcn_mfma_f32_16x16x32_bf16(af, bl1, acc1, 0, 0, 0);
      if (kt < 15) { cb0 = nb0; cb1 = nb1; cb2 = nb2; cb3 = nb3; }
    }
  }
#pragma unroll
  for (int jj = 0; jj < 4; jj++) {
    srw[(w * 16 + kg * 4 + jj) * 33 + l15]      = acc0[jj];
    srw[(w * 16 + kg * 4 + jj) * 33 + 16 + l15] = acc1[jj];
  }
  __syncthreads();
  {
    const int r = t & 63, ng = t >> 6;
    f32x4 u0 = (f32x4)(0.0f), u1 = (f32x4)(0.0f);
#pragma unroll
    for (int k = 0; k < 32; k++) {
      const float sv = srw[r * 33 + k];
      const f32x4 x0 = *(const f32x4*)&sXT[k * 32 + ng * 4];
      const f32x4 x1 = *(const f32x4*)&sXT[k * 32 + ng * 4 + 16];
#pragma unroll
      for (int q = 0; q < 4; q++) {
        u0[q] = fmaf(sv, x0[q], u0[q]);
        u1[q] = fmaf(sv, x1[q], u1[q]);
      }
    }
    float* up = uB + (rowbase + r) * D_STATE;
    *(f32x4*)(up + ng * 4) = u0;
    *(f32x4*)(up + ng * 4 + 16) = u1;
  }
}

// ========== k_scan: fp16 state broadcast + fdot2; BURN 80->64 (80 serial steps) ==========
__global__ void k_scan(const float* __restrict__ uB, const float* __restrict__ A_bar,
                       bf16* __restrict__ Sb, float* __restrict__ fs) {
  __shared__ half_t hs[256];          // 8 groups x 32 fp16 state
  const int t = threadIdx.x;
  const int g = t >> 5, n = t & 31;
  const int chain = blockIdx.x * 8 + g;
  const int b = chain >> 8;
  const int ch = chain & 255;
  const int cs = ch * CHUNK;
  const int t0 = cs - BURN;
  const int ce = cs + CHUNK;

  half2_t ah[16];
#pragma unroll
  for (int k = 0; k < 16; k++) {
    ah[k][0] = (half_t)A_bar[n * 32 + 2 * k];
    ah[k][1] = (half_t)A_bar[n * 32 + 2 * k + 1];
  }
#pragma unroll
  for (int k = 0; k < 16; k++) asm volatile("" : "+v"(ah[k]));  // pin: no remat/reload

  const float* ub = uB + (long)b * SEQ * D_STATE + n;
  bf16* sp = Sb + ((long)b * SEQ + cs) * D_STATE + n;
  half_t* myslot = &hs[g * 32];

  float s = 0.f;
  float ubuf[8], unext[8];
#pragma unroll
  for (int i = 0; i < 8; i++) {
    const int tt = t0 + i;
    ubuf[i] = (tt >= 0) ? ub[(long)tt * D_STATE] : 0.f;
  }
  for (int tg = t0; tg < ce; tg += 8) {
    const int tn = tg + 8;
#pragma unroll
    for (int i = 0; i < 8; i++) {
      const int tt = tn + i;
      unext[i] = (tt >= 0 && tt < ce) ? ub[(long)tt * D_STATE] : 0.f;
    }
#pragma unroll
    for (int i = 0; i < 8; i++) {
      const int tt = tg + i;
      myslot[n] = (half_t)s;   // ds_write_b16, wave-ordered before reads
      const half8 h0 = *(const half8*)(myslot + 0);
      const half8 h1 = *(const half8*)(myslot + 8);
      const half8 h2 = *(const half8*)(myslot + 16);
      const half8 h3 = *(const half8*)(myslot + 24);
      float acc0 = ubuf[i], acc1 = 0.f, acc2 = 0.f, acc3 = 0.f;
#if __has_builtin(__builtin_amdgcn_fdot2)
#pragma unroll
      for (int j = 0; j < 4; j++) {
        acc0 = __builtin_amdgcn_fdot2(ah[j],      ((const half2_t*)&h0)[j], acc0, false);
        acc1 = __builtin_amdgcn_fdot2(ah[4 + j],  ((const half2_t*)&h1)[j], acc1, false);
        acc2 = __builtin_amdgcn_fdot2(ah[8 + j],  ((const half2_t*)&h2)[j], acc2, false);
        acc3 = __builtin_amdgcn_fdot2(ah[12 + j], ((const half2_t*)&h3)[j], acc3, false);
      }
#else
#pragma unroll
      for (int j = 0; j < 4; j++) {
#pragma unroll
        for (int q = 0; q < 2; q++) {
          acc0 = fmaf((float)ah[j][q],      (float)((const half2_t*)&h0)[j][q], acc0);
          acc1 = fmaf((float)ah[4 + j][q],  (float)((const half2_t*)&h1)[j][q], acc1);
          acc2 = fmaf((float)ah[8 + j][q],  (float)((const half2_t*)&h2)[j][q], acc2);
          acc3 = fmaf((float)ah[12 + j][q], (float)((const half2_t*)&h3)[j][q], acc3);
        }
      }
#endif
      const float z = (acc0 + acc1) + (acc2 + acc3);
      const float e = __expf(2.f * z);
      const float r = __builtin_amdgcn_rcpf(e + 1.f);
      s = fmaf(-2.f, r, 1.f);
      if (tt >= cs) sp[(long)(tt - cs) * D_STATE] = (bf16)s;
    }
#pragma unroll
    for (int i = 0; i < 8; i++) ubuf[i] = unext[i];
  }
  if (ch == NCHUNK - 1) fs[b * D_STATE + n] = s;
}

// ====== k_out: r13/r15-proven 128x128 staged tile (frozen) ======
__device__ __forceinline__ void stage_tile(const void* gbase, long row0, long rowStrideB,
                                           int kByte, void* lds, int w, int lane) {
#pragma unroll
  for (int j = 0; j < 2; j++) {
    const int base_off = (w << 11) + (j << 10);
    const int boff = base_off + (lane << 4);
    const int r = boff >> 6;
    const int s = (boff >> 4) & 3;
    const int cb = ((s ^ (r & 3)) << 4);
    const char* src = (const char*)gbase + (row0 + r) * rowStrideB + kByte + cb;
    __builtin_amdgcn_global_load_lds(
        (const __attribute__((address_space(1))) void*)src,
        (__attribute__((address_space(3))) void*)((char*)lds + base_off), 16, 0, 0);
  }
}

__global__ __launch_bounds__(256) void k_out(const bf16* __restrict__ xb,
                                             const bf16* __restrict__ WD,
                                             const bf16* __restrict__ Sb,
                                             const bf16* __restrict__ CW,
                                             const float* __restrict__ bias,
                                             float* __restrict__ out) {
  __shared__ bf16 As[2][128 * 32];
  __shared__ bf16 Bs[2][128 * 32];
  const int tid = threadIdx.x;
  const int w = tid >> 6, lane = tid & 63;
  const int swz = (blockIdx.x & 7) * 128 + (blockIdx.x >> 3);
  const int bm = swz >> 2, bn = swz & 3;
  const long rowbase = (long)bm * 128;
  const long colbase = (long)bn * 128;
  const int wr = w >> 1, wc = w & 1;
  const int l15 = lane & 15, kg = lane >> 4;
  const int kgs = kg ^ (l15 & 3);

  f32x4 acc[4][4];
#pragma unroll
  for (int m = 0; m < 4; m++)
#pragma unroll
    for (int n = 0; n < 4; n++) acc[m][n] = (f32x4)(0.0f);

  const int aoff = (wr * 64 + l15) * 32 + kgs * 8;
  const int boff = (wc * 64 + l15) * 32 + kgs * 8;

  auto STAGE = [&](int ti, int b) {
    if (ti < 16) {
      stage_tile(xb, rowbase, 1024, ti * 64, &As[b][0], w, lane);
      stage_tile(WD, colbase, 1024, ti * 64, &Bs[b][0], w, lane);
    } else {
      stage_tile(Sb, rowbase, 64, 0, &As[b][0], w, lane);
      stage_tile(CW, colbase, 64, 0, &Bs[b][0], w, lane);
    }
  };

  STAGE(0, 0);
  __syncthreads();
#pragma unroll 1
  for (int kt = 0; kt < 17; kt++) {
    const int cur = kt & 1;
    if (kt < 16) STAGE(kt + 1, cur ^ 1);
    bf16x8 af[4], bfr[4];
#pragma unroll
    for (int m = 0; m < 4; m++) af[m] = *(const bf16x8*)&As[cur][aoff + m * 16 * 32];
#pragma unroll
    for (int n = 0; n < 4; n++) bfr[n] = *(const bf16x8*)&Bs[cur][boff + n * 16 * 32];
#pragma unroll
    for (int m = 0; m < 4; m++)
#pragma unroll
      for (int n = 0; n < 4; n++)
        acc[m][n] = __builtin_amdgcn_mfma_f32_16x16x32_bf16(af[m], bfr[n], acc[m][n], 0, 0, 0);
    __syncthreads();
  }
#pragma unroll
  for (int n = 0; n < 4; n++) {
    const int e = (int)colbase + wc * 64 + n * 16 + l15;
    const float bv = bias[e];
#pragma unroll
    for (int m = 0; m < 4; m++) {
      const long r0 = rowbase + wr * 64 + m * 16 + kg * 4;
      const f32x4 v = acc[m][n];
#pragma unroll
      for (int jj = 0; jj < 4; jj++) out[(r0 + jj) * (long)D_MODEL + e] = v[jj] + bv;
    }
  }
}

extern "C" void kernel_launch(void* const* d_in, const int* in_sizes, int n_in,
                              void* d_out, int out_size, void* d_ws, size_t ws_size,
                              hipStream_t stream) {
  const float* x      = (const float*)d_in[0];
  const float* A      = (const float*)d_in[1];
  const float* B      = (const float*)d_in[2];
  const float* C      = (const float*)d_in[3];
  const float* Dv     = (const float*)d_in[4];
  const float* log_dt = (const float*)d_in[5];
  const float* W      = (const float*)d_in[6];
  const float* b_out  = (const float*)d_in[7];
  float* out = (float*)d_out;
  float* fs  = out + (long)MROWS * D_MODEL;  // final_state (8x32) after y

  char* ws = (char*)d_ws;
  float* A_bar = (float*)(ws + 0);                    // 4 KB
  float* XTs   = (float*)(ws + (4L << 10));           // 4 KB (dt * X^T)
  bf16*  CW    = (bf16*)(ws + (68L << 10));           // 32 KB
  bf16*  WD    = (bf16*)(ws + (100L << 10));          // 512 KB
  bf16*  Sb    = (bf16*)(ws + (612L << 10));          // 2 MB
  float* uB    = (float*)(ws + (2660L << 10));        // 4 MB
  bf16*  xb    = (bf16*)(ws + (6756L << 10));         // 32 MB

  k_pre<<<dim3(33), dim3(256), 0, stream>>>(A, C, Dv, log_dt, W, A_bar, XTs, CW, WD);
  k_uB<<<dim3(MROWS / 64), dim3(256), 0, stream>>>(x, B, XTs, uB, xb);
  k_scan<<<dim3(256), dim3(256), 0, stream>>>(uB, A_bar, Sb, fs);
  k_out<<<dim3((MROWS / 128) * (D_MODEL / 128)), dim3(256), 0, stream>>>(xb, WD, Sb, CW, b_out, out);
}

// Round 17
// 87.728 us; speedup vs baseline: 1.0166x; 1.0166x over previous
//
#include <hip/hip_runtime.h>
#include <hip/hip_bf16.h>

#define D_MODEL 512
#define D_STATE 32
#define BATCH 8
#define SEQ 4096
#define MROWS (BATCH * SEQ)

typedef __bf16 bf16;
typedef __bf16 bf16x4 __attribute__((ext_vector_type(4)));
typedef __bf16 bf16x8 __attribute__((ext_vector_type(8)));
typedef float f32x4 __attribute__((ext_vector_type(4)));
typedef _Float16 half_t;
typedef _Float16 half2_t __attribute__((ext_vector_type(2)));
typedef _Float16 half8 __attribute__((ext_vector_type(8)));

#define CHUNK 16
#define BURN 64
#define NCHUNK (SEQ / CHUNK)   // 256 chunks per batch, 2048 chains

__device__ __forceinline__ bf16x8 cvt8(const f32x4 a, const f32x4 b) {
  bf16x8 h;
  h[0] = (bf16)a[0]; h[1] = (bf16)a[1]; h[2] = (bf16)a[2]; h[3] = (bf16)a[3];
  h[4] = (bf16)b[0]; h[5] = (bf16)b[1]; h[6] = (bf16)b[2]; h[7] = (bf16)b[3];
  return h;
}

// ================= k_pre: block 0 = dt/X/A_bar/XTs; blocks 1..16 CW; 17..32 WD ============
__global__ __launch_bounds__(256) void k_pre(
    const float* __restrict__ A, const float* __restrict__ C, const float* __restrict__ Dv,
    const float* __restrict__ log_dt, const float* __restrict__ W,
    float* __restrict__ A_bar, float* __restrict__ XTs,
    bf16* __restrict__ CW, bf16* __restrict__ WD) {
  __shared__ float Xs[32][32];
  const int bid = blockIdx.x, t = threadIdx.x;
  float* Xf = &Xs[0][0];

  if (bid == 0) {
    {
      float v0 = __expf(log_dt[t]);
      float v1 = __expf(log_dt[t + 256]);
      v0 = fminf(fmaxf(v0, 1e-4f), 1.0f);
      v1 = fminf(fmaxf(v1, 1e-4f), 1.0f);
      Xf[t] = v0 + v1;
    }
    __syncthreads();
    for (int s2 = 128; s2 > 0; s2 >>= 1) {
      if (t < s2) Xf[t] += Xf[t + s2];
      __syncthreads();
    }
    const float dtv = Xf[0] * (1.0f / 512.0f);
    __syncthreads();
    {
      const int i0 = 4 * t;
      const f32x4 av = *(const f32x4*)(A + i0);
      f32x4 mv;
#pragma unroll
      for (int q = 0; q < 4; q++) {
        const int r = (i0 + q) >> 5, c = (i0 + q) & 31;
        mv[q] = (r == c ? 1.0f : 0.0f) - 0.5f * dtv * av[q];
      }
      *(f32x4*)(Xf + i0) = mv;
    }
    __syncthreads();
    if (t < 32) {
      const int j = t;
      float xcol[32];
#pragma unroll
      for (int i = 0; i < 32; i++) {
        float s0 = 0.f, s1 = 0.f, s2 = 0.f, s3 = 0.f;
#pragma unroll
        for (int k = 0; k < 32; k += 4) {
          if (k < i)     s0 -= Xf[i * 32 + k]     * xcol[k];
          if (k + 1 < i) s1 -= Xf[i * 32 + k + 1] * xcol[k + 1];
          if (k + 2 < i) s2 -= Xf[i * 32 + k + 2] * xcol[k + 2];
          if (k + 3 < i) s3 -= Xf[i * 32 + k + 3] * xcol[k + 3];
        }
        const float num = (i == j ? 1.0f : 0.0f) + ((s0 + s1) + (s2 + s3));
        xcol[i] = (i >= j) ? num / Xf[i * 32 + i] : 0.0f;
      }
#pragma unroll
      for (int i = 0; i < 32; i++) Xs[i][j] = xcol[i];
    }
    __syncthreads();
    {
      const int i0 = 4 * t;
      const int r = t >> 3;
      f32x4 ov;
#pragma unroll
      for (int q = 0; q < 4; q++) {
        const int c = (i0 + q) & 31;
        float s = 0.f;
#pragma unroll
        for (int k = 0; k < 32; k++) {
          const float p2 = (r == k ? 1.0f : 0.0f) + 0.5f * dtv * A[r * 32 + k];
          s = fmaf(p2, Xf[k * 32 + c], s);
        }
        ov[q] = s;
      }
      *(f32x4*)(A_bar + i0) = ov;
    }
#pragma unroll
    for (int i = 0; i < 4; i++) {
      const int idx = t + i * 256;
      const int k = idx >> 5, n = idx & 31;
      XTs[idx] = dtv * Xf[n * 32 + k];
    }
  } else if (bid <= 16) {
    const int w = t >> 6, lane = t & 63;
    const int l15 = lane & 15, kg = lane >> 4;
    const int m = w & 1, nf = w >> 1;
    const int eb = (bid - 1) * 32;
    const float* wp = W + (long)(eb + m * 16 + l15) * D_MODEL + kg * 8;
    const int ncol = nf * 16 + l15;
    f32x4 acc = (f32x4)(0.0f);
#pragma unroll 1
    for (int kt = 0; kt < 16; kt++) {
      const f32x4 w0 = *(const f32x4*)(wp + kt * 32);
      const f32x4 w1 = *(const f32x4*)(wp + kt * 32 + 4);
      const bf16x8 af = cvt8(w0, w1);
      bf16x8 bf;
#pragma unroll
      for (int j = 0; j < 8; j++)
        bf[j] = (bf16)C[(kt * 32 + kg * 8 + j) * D_STATE + ncol];
      acc = __builtin_amdgcn_mfma_f32_16x16x32_bf16(af, bf, acc, 0, 0, 0);
    }
#pragma unroll
    for (int jj = 0; jj < 4; jj++)
      CW[(eb + m * 16 + kg * 4 + jj) * D_STATE + ncol] = (bf16)acc[jj];
  } else {
#pragma unroll
    for (int jj = 0; jj < 16; jj++) {
      const int i = (bid - 17) * 16384 + jj * 1024 + t * 4;
      const f32x4 wv = *(const f32x4*)(W + i);
      const f32x4 dv = *(const f32x4*)(Dv + (i & 511));
      bf16x4 h;
#pragma unroll
      for (int q = 0; q < 4; q++) h[q] = (bf16)(wv[q] * dv[q]);
      *(bf16x4*)(WD + i) = h;
    }
  }
}

// ========= k_uB: BK=64 phases, 3 blocks/CU, global_load_lds staging (r16, frozen) =========
__device__ __forceinline__ void stage_x2(const float* __restrict__ x, long rowbase,
                                         int ph, void* lds, int t) {
#pragma unroll
  for (int j = 0; j < 4; j++) {
    const int boff = j * 4096 + t * 16;
    const int r = boff >> 8;
    const int s = (boff >> 4) & 15;
    const int cb = (s ^ (r & 15)) << 4;
    const char* src = (const char*)(x + (rowbase + r) * D_MODEL) + ph * 256 + cb;
    const int udst = j * 4096 + ((t >> 6) << 10);
    __builtin_amdgcn_global_load_lds(
        (const __attribute__((address_space(1))) void*)src,
        (__attribute__((address_space(3))) void*)((char*)lds + udst), 16, 0, 0);
  }
}

__global__ __launch_bounds__(256, 3) void k_uB(
    const float* __restrict__ x, const float* __restrict__ B,
    const float* __restrict__ XTs,
    float* __restrict__ uB, bf16* __restrict__ xb) {
  __shared__ float xs[2][64 * 64];
  __shared__ float sXT[1024];
  __shared__ float srw[64 * 33];
  const int t = threadIdx.x, w = t >> 6, lane = t & 63;
  const int l15 = lane & 15, kg = lane >> 4;
  const long rowbase = (long)blockIdx.x * 64;

#pragma unroll
  for (int i = 0; i < 4; i++) sXT[t + i * 256] = XTs[t + i * 256];

  const int arow = w * 16 + l15;
  bf16* xo = xb + (rowbase + arow) * D_MODEL + kg * 8;
  const float* bp0 = B + l15 * D_MODEL + kg * 8;
  const float* bp1 = B + (16 + l15) * D_MODEL + kg * 8;
  const int rkey = arow & 15;

  f32x4 acc0 = (f32x4)(0.0f), acc1 = (f32x4)(0.0f);
  f32x4 cb0, cb1, cb2, cb3, nb0, nb1, nb2, nb3;

  stage_x2(x, rowbase, 0, &xs[0][0], t);
  cb0 = *(const f32x4*)(bp0); cb1 = *(const f32x4*)(bp0 + 4);
  cb2 = *(const f32x4*)(bp1); cb3 = *(const f32x4*)(bp1 + 4);

#pragma unroll 1
  for (int ph = 0; ph < 8; ph++) {
    __syncthreads();
    if (ph < 7) stage_x2(x, rowbase, ph + 1, &xs[(ph + 1) & 1][0], t);
    const float* xbuf = &xs[ph & 1][arow * 64];
#pragma unroll
    for (int h = 0; h < 2; h++) {
      const int kt = ph * 2 + h;
      if (kt < 15) {
        const int o = (kt + 1) * 32;
        nb0 = *(const f32x4*)(bp0 + o); nb1 = *(const f32x4*)(bp0 + o + 4);
        nb2 = *(const f32x4*)(bp1 + o); nb3 = *(const f32x4*)(bp1 + o + 4);
      }
      const int sl0 = ((h * 8 + kg * 2) ^ rkey) << 2;
      const int sl1 = ((h * 8 + kg * 2 + 1) ^ rkey) << 2;
      const f32x4 a0 = *(const f32x4*)(xbuf + sl0);
      const f32x4 a1 = *(const f32x4*)(xbuf + sl1);
      const bf16x8 af = cvt8(a0, a1);
      *(bf16x8*)(xo + kt * 32) = af;
      const bf16x8 bh0 = cvt8(cb0, cb1);
      const bf16x8 bh1 = cvt8(cb2, cb3);
      bf16x8 bl0, bl1;
#pragma unroll
      for (int q = 0; q < 4; q++) {
        bl0[q]     = (bf16)(cb0[q] - (float)bh0[q]);
        bl0[q + 4] = (bf16)(cb1[q] - (float)bh0[q + 4]);
        bl1[q]     = (bf16)(cb2[q] - (float)bh1[q]);
        bl1[q + 4] = (bf16)(cb3[q] - (float)bh1[q + 4]);
      }
      acc0 = __builtin_amdgcn_mfma_f32_16x16x32_bf16(af, bh0, acc0, 0, 0, 0);
      acc0 = __builtin_amdgcn_mfma_f32_16x16x32_bf16(af, bl0, acc0, 0, 0, 0);
      acc1 = __builtin_amdgcn_mfma_f32_16x16x32_bf16(af, bh1, acc1, 0, 0, 0);
      acc1 = __builtin_amdgcn_mfma_f32_16x16x32_bf16(af, bl1, acc1, 0, 0, 0);
      if (kt < 15) { cb0 = nb0; cb1 = nb1; cb2 = nb2; cb3 = nb3; }
    }
  }
#pragma unroll
  for (int jj = 0; jj < 4; jj++) {
    srw[(w * 16 + kg * 4 + jj) * 33 + l15]      = acc0[jj];
    srw[(w * 16 + kg * 4 + jj) * 33 + 16 + l15] = acc1[jj];
  }
  __syncthreads();
  {
    const int r = t & 63, ng = t >> 6;
    f32x4 u0 = (f32x4)(0.0f), u1 = (f32x4)(0.0f);
#pragma unroll
    for (int k = 0; k < 32; k++) {
      const float sv = srw[r * 33 + k];
      const f32x4 x0 = *(const f32x4*)&sXT[k * 32 + ng * 4];
      const f32x4 x1 = *(const f32x4*)&sXT[k * 32 + ng * 4 + 16];
#pragma unroll
      for (int q = 0; q < 4; q++) {
        u0[q] = fmaf(sv, x0[q], u0[q]);
        u1[q] = fmaf(sv, x1[q], u1[q]);
      }
    }
    float* up = uB + (rowbase + r) * D_STATE;
    *(f32x4*)(up + ng * 4) = u0;
    *(f32x4*)(up + ng * 4 + 16) = u1;
  }
}

// ========== k_scan: fp16 state broadcast + fdot2 (frozen) ==========
__global__ void k_scan(const float* __restrict__ uB, const float* __restrict__ A_bar,
                       bf16* __restrict__ Sb, float* __restrict__ fs) {
  __shared__ half_t hs[256];
  const int t = threadIdx.x;
  const int g = t >> 5, n = t & 31;
  const int chain = blockIdx.x * 8 + g;
  const int b = chain >> 8;
  const int ch = chain & 255;
  const int cs = ch * CHUNK;
  const int t0 = cs - BURN;
  const int ce = cs + CHUNK;

  half2_t ah[16];
#pragma unroll
  for (int k = 0; k < 16; k++) {
    ah[k][0] = (half_t)A_bar[n * 32 + 2 * k];
    ah[k][1] = (half_t)A_bar[n * 32 + 2 * k + 1];
  }
#pragma unroll
  for (int k = 0; k < 16; k++) asm volatile("" : "+v"(ah[k]));

  const float* ub = uB + (long)b * SEQ * D_STATE + n;
  bf16* sp = Sb + ((long)b * SEQ + cs) * D_STATE + n;
  half_t* myslot = &hs[g * 32];

  float s = 0.f;
  float ubuf[8], unext[8];
#pragma unroll
  for (int i = 0; i < 8; i++) {
    const int tt = t0 + i;
    ubuf[i] = (tt >= 0) ? ub[(long)tt * D_STATE] : 0.f;
  }
  for (int tg = t0; tg < ce; tg += 8) {
    const int tn = tg + 8;
#pragma unroll
    for (int i = 0; i < 8; i++) {
      const int tt = tn + i;
      unext[i] = (tt >= 0 && tt < ce) ? ub[(long)tt * D_STATE] : 0.f;
    }
#pragma unroll
    for (int i = 0; i < 8; i++) {
      const int tt = tg + i;
      myslot[n] = (half_t)s;
      const half8 h0 = *(const half8*)(myslot + 0);
      const half8 h1 = *(const half8*)(myslot + 8);
      const half8 h2 = *(const half8*)(myslot + 16);
      const half8 h3 = *(const half8*)(myslot + 24);
      float acc0 = ubuf[i], acc1 = 0.f, acc2 = 0.f, acc3 = 0.f;
#if __has_builtin(__builtin_amdgcn_fdot2)
#pragma unroll
      for (int j = 0; j < 4; j++) {
        acc0 = __builtin_amdgcn_fdot2(ah[j],      ((const half2_t*)&h0)[j], acc0, false);
        acc1 = __builtin_amdgcn_fdot2(ah[4 + j],  ((const half2_t*)&h1)[j], acc1, false);
        acc2 = __builtin_amdgcn_fdot2(ah[8 + j],  ((const half2_t*)&h2)[j], acc2, false);
        acc3 = __builtin_amdgcn_fdot2(ah[12 + j], ((const half2_t*)&h3)[j], acc3, false);
      }
#else
#pragma unroll
      for (int j = 0; j < 4; j++) {
#pragma unroll
        for (int q = 0; q < 2; q++) {
          acc0 = fmaf((float)ah[j][q],      (float)((const half2_t*)&h0)[j][q], acc0);
          acc1 = fmaf((float)ah[4 + j][q],  (float)((const half2_t*)&h1)[j][q], acc1);
          acc2 = fmaf((float)ah[8 + j][q],  (float)((const half2_t*)&h2)[j][q], acc2);
          acc3 = fmaf((float)ah[12 + j][q], (float)((const half2_t*)&h3)[j][q], acc3);
        }
      }
#endif
      const float z = (acc0 + acc1) + (acc2 + acc3);
      const float e = __expf(2.f * z);
      const float r = __builtin_amdgcn_rcpf(e + 1.f);
      s = fmaf(-2.f, r, 1.f);
      if (tt >= cs) sp[(long)(tt - cs) * D_STATE] = (bf16)s;
    }
#pragma unroll
    for (int i = 0; i < 8; i++) ubuf[i] = unext[i];
  }
  if (ch == NCHUNK - 1) fs[b * D_STATE + n] = s;
}

// ====== k_out v2: 128x128 tile, TRIPLE-buffered LDS + counted vmcnt (T4) ======
// Per iter: each wave waits vmcnt(4) = ITS OWN stage(kt) loads done (stage(kt+1)
// stays in flight), then s_barrier collects all waves' certifications -> tile
// complete. STAGE(kt+2) issues after the barrier; it overwrites buf (kt-1)%3,
// whose reads completed before every wave ARRIVED at this barrier. No drain-to-0
// in the main loop (final iter only).
__device__ __forceinline__ void stage_tile(const void* gbase, long row0, long rowStrideB,
                                           int kByte, void* lds, int w, int lane) {
#pragma unroll
  for (int j = 0; j < 2; j++) {
    const int base_off = (w << 11) + (j << 10);
    const int boff = base_off + (lane << 4);
    const int r = boff >> 6;
    const int s = (boff >> 4) & 3;
    const int cb = ((s ^ (r & 3)) << 4);
    const char* src = (const char*)gbase + (row0 + r) * rowStrideB + kByte + cb;
    __builtin_amdgcn_global_load_lds(
        (const __attribute__((address_space(1))) void*)src,
        (__attribute__((address_space(3))) void*)((char*)lds + base_off), 16, 0, 0);
  }
}

__global__ __launch_bounds__(256) void k_out(const bf16* __restrict__ xb,
                                             const bf16* __restrict__ WD,
                                             const bf16* __restrict__ Sb,
                                             const bf16* __restrict__ CW,
                                             const float* __restrict__ bias,
                                             float* __restrict__ out) {
  __shared__ bf16 As[3][128 * 32];   // 3 x 8 KB
  __shared__ bf16 Bs[3][128 * 32];   // 3 x 8 KB  (48 KB total -> 3 blocks/CU)
  const int tid = threadIdx.x;
  const int w = tid >> 6, lane = tid & 63;
  const int swz = (blockIdx.x & 7) * 128 + (blockIdx.x >> 3);
  const int bm = swz >> 2, bn = swz & 3;
  const long rowbase = (long)bm * 128;
  const long colbase = (long)bn * 128;
  const int wr = w >> 1, wc = w & 1;
  const int l15 = lane & 15, kg = lane >> 4;
  const int kgs = kg ^ (l15 & 3);

  f32x4 acc[4][4];
#pragma unroll
  for (int m = 0; m < 4; m++)
#pragma unroll
    for (int n = 0; n < 4; n++) acc[m][n] = (f32x4)(0.0f);

  const int aoff = (wr * 64 + l15) * 32 + kgs * 8;
  const int boff = (wc * 64 + l15) * 32 + kgs * 8;

  auto STAGE = [&](int ti, int b) {
    if (ti < 16) {
      stage_tile(xb, rowbase, 1024, ti * 64, &As[b][0], w, lane);
      stage_tile(WD, colbase, 1024, ti * 64, &Bs[b][0], w, lane);
    } else {
      stage_tile(Sb, rowbase, 64, 0, &As[b][0], w, lane);
      stage_tile(CW, colbase, 64, 0, &Bs[b][0], w, lane);
    }
  };

  STAGE(0, 0);          // 4 loads/thread in flight
  STAGE(1, 1);          // 8 loads/thread in flight
#pragma unroll 1
  for (int kt = 0; kt < 17; kt++) {
    const int cur = kt % 3;
    if (kt < 16) {
      asm volatile("s_waitcnt vmcnt(4)" ::: "memory");  // stage(kt) landed; stage(kt+1) flying
    } else {
      asm volatile("s_waitcnt vmcnt(0)" ::: "memory");  // final tile: drain
    }
    __builtin_amdgcn_s_barrier();     // all waves certified their stage(kt) portion
    bf16x8 af[4], bfr[4];
#pragma unroll
    for (int m = 0; m < 4; m++) af[m] = *(const bf16x8*)&As[cur][aoff + m * 16 * 32];
#pragma unroll
    for (int n = 0; n < 4; n++) bfr[n] = *(const bf16x8*)&Bs[cur][boff + n * 16 * 32];
#pragma unroll
    for (int m = 0; m < 4; m++)
#pragma unroll
      for (int n = 0; n < 4; n++)
        acc[m][n] = __builtin_amdgcn_mfma_f32_16x16x32_bf16(af[m], bfr[n], acc[m][n], 0, 0, 0);
    if (kt + 2 <= 16) STAGE(kt + 2, (kt + 2) % 3);  // overwrites buf (kt-1)%3: safe past barrier
  }
#pragma unroll
  for (int n = 0; n < 4; n++) {
    const int e = (int)colbase + wc * 64 + n * 16 + l15;
    const float bv = bias[e];
#pragma unroll
    for (int m = 0; m < 4; m++) {
      const long r0 = rowbase + wr * 64 + m * 16 + kg * 4;
      const f32x4 v = acc[m][n];
#pragma unroll
      for (int jj = 0; jj < 4; jj++) out[(r0 + jj) * (long)D_MODEL + e] = v[jj] + bv;
    }
  }
}

extern "C" void kernel_launch(void* const* d_in, const int* in_sizes, int n_in,
                              void* d_out, int out_size, void* d_ws, size_t ws_size,
                              hipStream_t stream) {
  const float* x      = (const float*)d_in[0];
  const float* A      = (const float*)d_in[1];
  const float* B      = (const float*)d_in[2];
  const float* C      = (const float*)d_in[3];
  const float* Dv     = (const float*)d_in[4];
  const float* log_dt = (const float*)d_in[5];
  const float* W      = (const float*)d_in[6];
  const float* b_out  = (const float*)d_in[7];
  float* out = (float*)d_out;
  float* fs  = out + (long)MROWS * D_MODEL;  // final_state (8x32) after y

  char* ws = (char*)d_ws;
  float* A_bar = (float*)(ws + 0);                    // 4 KB
  float* XTs   = (float*)(ws + (4L << 10));           // 4 KB (dt * X^T)
  bf16*  CW    = (bf16*)(ws + (68L << 10));           // 32 KB
  bf16*  WD    = (bf16*)(ws + (100L << 10));          // 512 KB
  bf16*  Sb    = (bf16*)(ws + (612L << 10));          // 2 MB
  float* uB    = (float*)(ws + (2660L << 10));        // 4 MB
  bf16*  xb    = (bf16*)(ws + (6756L << 10));         // 32 MB

  k_pre<<<dim3(33), dim3(256), 0, stream>>>(A, C, Dv, log_dt, W, A_bar, XTs, CW, WD);
  k_uB<<<dim3(MROWS / 64), dim3(256), 0, stream>>>(x, B, XTs, uB, xb);
  k_scan<<<dim3(256), dim3(256), 0, stream>>>(uB, A_bar, Sb, fs);
  k_out<<<dim3((MROWS / 128) * (D_MODEL / 128)), dim3(256), 0, stream>>>(xb, WD, Sb, CW, b_out, out);
}